// Round 8
// baseline (279.808 us; speedup 1.0000x reference)
//
#include <hip/hip_runtime.h>
#include <hip/hip_fp16.h>

#define CV_B 8
#define CV_C 128
#define CV_H 128
#define CV_W 240
#define CV_V 48
#define PLANE (CV_H * CV_W)

#define NCP 4                  // c-pairs per stage (= 8 channels)
#define NSTAGE 16              // 16 stages x 8 c = 128 c
#define GUARDF 12              // guard vec4s (= 48 half2 words) left of each R row
#define LROW 60                // L row: 60 vec4 (240 half2 c-pair words)
#define RROW (GUARDF + LROW)   // 72 vec4 = 1152 B per R row

// LDS element is a TRUE LLVM vector (ext_vector_type): float4/int4 are
// structs -> SROA splits their LDS accesses into 4x ds_read_b32 (16B lane
// stride -> 8-way bank conflict, was 2.36e7 cycles). ext_vector loads stay
// single ds_read_b128, conflict-free (verified: conflicts dropped to 8192).
typedef unsigned int u32x4 __attribute__((ext_vector_type(4)));

static __device__ __forceinline__ __half2 bc_h2(unsigned v) {
    return __builtin_bit_cast(__half2, v);
}
static __device__ __forceinline__ unsigned bc_u(__half2 v) {
    return __builtin_bit_cast(unsigned, v);
}

// Occupancy lever without changing the proven 256-thread/4-wave block:
// R5 measured 16 waves/CU (grid 1024 x 4 waves = hard 50% cap) with no pipe
// above 25% busy. Double the GRID instead of the block: 2048 blocks, each
// covering 24 of 48 disparities. 8 blocks/CU x 4 waves = 32 waves/CU.
// Twin blocks (same y,b) are adjacent in blockIdx.x -> dispatched together
// -> second block's global reads L2-hit (row pair = 245 KB << 4 MB/XCD).
// Disparity split by PARITY of i-group so M0P is block-uniform:
//   iblk=0: groups g=2wv   (i=12wv..12wv+5),  M0P=8, rb = u + 10 - 3wv
//   iblk=1: groups g=2wv+1 (i=12wv+6..+11),   M0P=6, rb = u + 9 - 3wv
// Derivation: R word for (x,i) is (x-i)+48, x=4u+xx, i=6g+r; kernel reads
// word 4rb + xx + M0P - r; equality gives rb = u + (48-6g-M0P)/4, integer
// for the above (M0P,g-parity) pairing. Index xx+M0P-r ranges 3..11 (M0P=8)
// / 1..9 (M0P=6) within the 12-word window; rb in [0,69], rb+2 <= 71 = RROW-1.
template <int M0P>
static __device__ __forceinline__ void compute_stage(
        const u32x4 (*__restrict__ sLp)[LROW],
        const u32x4 (*__restrict__ sRp)[RROW],
        int u, int rb, __half2 acc[4][6])
{
#pragma unroll
    for (int cp = 0; cp < NCP; ++cp) {
        const u32x4 lvv = sLp[cp][u];            // ds_read_b128
        const u32x4 rv0 = sRp[cp][rb];           // ds_read_b128 x3
        const u32x4 rv1 = sRp[cp][rb + 1];
        const u32x4 rv2 = sRp[cp][rb + 2];

        __half2 lw[4];
        lw[0] = bc_h2(lvv.x); lw[1] = bc_h2(lvv.y);
        lw[2] = bc_h2(lvv.z); lw[3] = bc_h2(lvv.w);
        __half2 rw[12];
        rw[0] = bc_h2(rv0.x); rw[1]  = bc_h2(rv0.y);
        rw[2] = bc_h2(rv0.z); rw[3]  = bc_h2(rv0.w);
        rw[4] = bc_h2(rv1.x); rw[5]  = bc_h2(rv1.y);
        rw[6] = bc_h2(rv1.z); rw[7]  = bc_h2(rv1.w);
        rw[8] = bc_h2(rv2.x); rw[9]  = bc_h2(rv2.y);
        rw[10] = bc_h2(rv2.z); rw[11] = bc_h2(rv2.w);
#pragma unroll
        for (int r = 0; r < 6; ++r) {
#pragma unroll
            for (int xx = 0; xx < 4; ++xx) {
                acc[xx][r] = __hfma2(lw[xx], rw[xx + M0P - r], acc[xx][r]);
            }
        }
    }
}

// launch_bounds(256,4): the proven-non-spilling bound (R5: VGPR=56, WRITE
// 46MB). Tighter bounds made the allocator slash below the 48-reg live set
// and spill acc to scratch (R3: 32 regs / 548MB writes, R4: 40 / 322MB).
__global__ __launch_bounds__(256, 4) void cost_volume_kernel(
        const float* __restrict__ Lf, const float* __restrict__ Rf,
        float* __restrict__ out)
{
    // ping-pong stage buffers: 2 x 4 cp x (60 + 72) vec4 = 16,896 B
    // 8 blocks/CU x 16.9 KB = 135 KB < 160 KB -> LDS fits at full residency.
    __shared__ u32x4 sL[2][NCP][LROW];
    __shared__ u32x4 sR[2][NCP][RROW];

    const int t    = threadIdx.x;
    const int iblk = blockIdx.x & 1;    // disparity parity half (block-uniform)
    const int y    = blockIdx.x >> 1;
    const int b    = blockIdx.y;
    const int wv   = t >> 6;            // wave id 0..3
    const int u    = t & 63;            // lane: x-group (x0 = 4u), u<60 active
    const bool act = (u < 60);
    const int x0 = 4 * u;

    const float* Lrow = Lf + (size_t)(b * CV_C) * PLANE + y * CV_W;
    const float* Rrow = Rf + (size_t)(b * CV_C) * PLANE + y * CV_W;

    // staging roles (same as R5): waves 0,1 stage L (2 c-pairs each); 2,3 stage R
    const int side = wv >> 1;
    const int a0   = (wv & 1) * 2;
    const float* Srow = side ? Rrow : Lrow;

    // ---- zero R guards once (both buffers; commits never write f < GUARDF) ----
    for (int idx = t; idx < 2 * NCP * GUARDF; idx += 256) {
        const int bi = idx / (NCP * GUARDF);
        const int rm = idx % (NCP * GUARDF);
        u32x4 z; z.x = 0u; z.y = 0u; z.z = 0u; z.w = 0u;
        sR[bi][rm / GUARDF][rm % GUARDF] = z;
    }

    float4 f0[2], f1[2];

    // ---- prologue: load + commit stage 0 into buffer 0 ----
    if (act) {
#pragma unroll
        for (int q = 0; q < 2; ++q) {
            const float* p = Srow + (size_t)(2 * (a0 + q)) * PLANE + x0;
            f0[q] = *(const float4*)p;            // row c   (960 B contiguous/inst)
            f1[q] = *(const float4*)(p + PLANE);  // row c+1
        }
#pragma unroll
        for (int q = 0; q < 2; ++q) {
            u32x4 w;
            w.x = bc_u(__floats2half2_rn(f0[q].x, f1[q].x));
            w.y = bc_u(__floats2half2_rn(f0[q].y, f1[q].y));
            w.z = bc_u(__floats2half2_rn(f0[q].z, f1[q].z));
            w.w = bc_u(__floats2half2_rn(f0[q].w, f1[q].w));
            if (side) sR[0][a0 + q][GUARDF + u] = w;   // ds_write_b128
            else      sL[0][a0 + q][u]          = w;
        }
    }
    __syncthreads();

    // ---- accumulators: thread tile = 4 x  X  6 i  (i = 12*wv + 6*iblk + r) ----
    __half2 acc[4][6];
#pragma unroll
    for (int xx = 0; xx < 4; ++xx)
#pragma unroll
        for (int r = 0; r < 6; ++r) acc[xx][r] = __floats2half2_rn(0.f, 0.f);

    const int rb = iblk ? (u + 9 - 3 * wv) : (u + 10 - 3 * wv);

    for (int s = 0; s < NSTAGE; ++s) {
        const int P = s & 1;
        const bool pf = (s + 1 < NSTAGE);

        // 1) issue next stage's global loads (in flight through compute)
        if (pf && act) {
#pragma unroll
            for (int q = 0; q < 2; ++q) {
                const float* p = Srow + (size_t)(8 * (s + 1) + 2 * (a0 + q)) * PLANE + x0;
                f0[q] = *(const float4*)p;
                f1[q] = *(const float4*)(p + PLANE);
            }
        }

        // 2) compute stage s from buf[P]: channels 8s .. 8s+7
        //    (block-uniform branch: iblk is constant per block)
        if (act) {
            if (iblk) compute_stage<6>(sL[P], sR[P], u, rb, acc);
            else      compute_stage<8>(sL[P], sR[P], u, rb, acc);
        }

        // 3) convert + commit stage s+1 into the other buffer (readers of
        //    buf[P^1] finished at the barrier ending stage s-1 -> race-free)
        if (pf && act) {
#pragma unroll
            for (int q = 0; q < 2; ++q) {
                u32x4 w;
                w.x = bc_u(__floats2half2_rn(f0[q].x, f1[q].x));
                w.y = bc_u(__floats2half2_rn(f0[q].y, f1[q].y));
                w.z = bc_u(__floats2half2_rn(f0[q].z, f1[q].z));
                w.w = bc_u(__floats2half2_rn(f0[q].w, f1[q].w));
                if (side) sR[P ^ 1][a0 + q][GUARDF + u] = w;
                else      sL[P ^ 1][a0 + q][u]          = w;
            }
        }
        if (pf) __syncthreads();   // single barrier per stage
    }

    // ---- epilogue: fold half2 (lo=even c, hi=odd c), scale, coalesced store ----
    if (act) {
#pragma unroll
        for (int r = 0; r < 6; ++r) {
            const int i = 12 * wv + 6 * iblk + r;
            float4 o;
            o.x = (__low2float(acc[0][r]) + __high2float(acc[0][r])) * (1.f / 128.f);
            o.y = (__low2float(acc[1][r]) + __high2float(acc[1][r])) * (1.f / 128.f);
            o.z = (__low2float(acc[2][r]) + __high2float(acc[2][r])) * (1.f / 128.f);
            o.w = (__low2float(acc[3][r]) + __high2float(acc[3][r])) * (1.f / 128.f);
            *(float4*)&out[(((size_t)b * CV_V + i) * CV_H + y) * CV_W + x0] = o;
        }
    }
}

extern "C" void kernel_launch(void* const* d_in, const int* in_sizes, int n_in,
                              void* d_out, int out_size, void* d_ws, size_t ws_size,
                              hipStream_t stream)
{
    const float* Lf = (const float*)d_in[0];
    const float* Rf = (const float*)d_in[1];
    float* o = (float*)d_out;
    dim3 grid(2 * CV_H, CV_B);   // two blocks (i-parity halves) per (y, b)
    dim3 block(256);
    hipLaunchKernelGGL(cost_volume_kernel, grid, block, 0, stream, Lf, Rf, o);
}